// Round 13
// baseline (161.126 us; speedup 1.0000x reference)
//
#include <hip/hip_runtime.h>

typedef _Float16 f16;
typedef _Float16 f16x4 __attribute__((ext_vector_type(4)));
typedef _Float16 f16x8 __attribute__((ext_vector_type(8)));
typedef float    f32x4 __attribute__((ext_vector_type(4)));

#define NB 32
#define ND 256
#define NT 1024
#define MAGIC64 0x5A5A3C3CA5A5C3C3ull

#define NPROD 2048
#define NCONS 512
#define NWPREP 32

// ---------------------------------------------------------------------------
// ONE dispatch, heterogeneous blocks, NO grid-wide co-residency requirement.
//
// Deadlock-freedom by slot counting: 256-thr blocks, LDS 33KB, VGPR<=128
// (__launch_bounds__(256,4)) -> 4 blocks/CU -> 1024 resident slots. Only 512
// consumer blocks exist, so even if ALL consumers are resident and spinning,
// >=511 slots hold runnable producers -> guaranteed progress under ANY
// dispatch order (correctness never depends on scheduling; G16-safe).
// Producers run at 16 waves/CU -> near-full HBM BW (R12's failure mode --
// 8 waves/CU, ~500 GB/s -- is structurally removed).
//
// blocks [0,2048):    producer p: IIR scan rows [4p,4p+4) (R6 node-1 body,
//                     one row/wave) -> y16, release cflags[p].
// blocks [2048,2560): consumer cb: b=cb>>4, tt=cb&15. Spin-acquire 64 cohort
//                     cflags + 32 wflags, then R11 bilinear body:
//                     out[b,t] = sum_n y[n,t]*(z[n,t]+1) - 70, z = Wm*y.
// blocks [2560,2592): wprep (R6 tail body) -> wf, release wflags.
//
// Handoff: producer __syncthreads + __threadfence + agent-scope release
// store; consumer per-lane agent-scope acquire loads + __syncthreads
// (R6/R9-validated; R9 replays proved stale-MAGIC spins are harmless:
// y16/wf bytes are identical every replay).
// ---------------------------------------------------------------------------
__global__ __launch_bounds__(256, 4) void dbnn_mega_kernel(
    const float* __restrict__ x, const float* __restrict__ tau_rise,
    const float* __restrict__ tau_decay, const float* __restrict__ omega,
    const float* __restrict__ W, f16* __restrict__ y16, f16* __restrict__ wf,
    unsigned long long* __restrict__ cflags,
    unsigned long long* __restrict__ wflags, float* __restrict__ out)
{
    __shared__ __align__(16) f16 Yl[16384];    // 32 KB (64 t x 256 m)
    __shared__ float sbuf[4][64];              // 1 KB cross-wave partials

    const int g    = blockIdx.x;
    const int tid  = threadIdx.x;
    const int lane = tid & 63;
    const int w    = tid >> 6;

    // ================= producers: IIR scan (R6 node-1 body) ===============
    if (g < NPROD) {
        const int row = g * 4 + w;              // b*ND + n
        const int n   = row & (ND - 1);

        const float td = tau_decay[n];
        const float tr = tau_rise[n];
        const float om = omega[n];
        const float ad = expf(-1.0f / td);
        const float am = expf(-(1.0f / tr + 1.0f / td));

        const float* xr = x + (size_t)row * NT + lane * 16;
        float xv[16];
        #pragma unroll
        for (int i = 0; i < 4; ++i) {
            f32x4 v = *reinterpret_cast<const f32x4*>(xr + i * 4);
            xv[i*4+0] = v[0]; xv[i*4+1] = v[1];
            xv[i*4+2] = v[2]; xv[i*4+3] = v[3];
        }

        // local (carry-free) inclusive scans, both states
        float ld[16], lm[16];
        float sd = 0.f, sm = 0.f;
        #pragma unroll
        for (int i = 0; i < 16; ++i) {
            sd = fmaf(ad, sd, xv[i]); ld[i] = sd;
            sm = fmaf(am, sm, xv[i]); lm[i] = sm;
        }

        // a^16 ladders
        float t2;
        t2 = ad * ad; t2 = t2 * t2; t2 = t2 * t2; float wd = t2 * t2;
        t2 = am * am; t2 = t2 * t2; t2 = t2 * t2; float wm = t2 * t2;

        // weighted Kogge-Stone across lanes
        float Xd = sd, Xm = sm;
        #pragma unroll
        for (int off = 1; off < 64; off <<= 1) {
            float pd = __shfl_up(Xd, off);
            float pm = __shfl_up(Xm, off);
            if (lane >= off) { Xd = fmaf(wd, pd, Xd); Xm = fmaf(wm, pm, Xm); }
            wd *= wd; wm *= wm;
        }
        float cd = __shfl_up(Xd, 1);
        float cm = __shfl_up(Xm, 1);
        if (lane == 0) { cd = 0.f; cm = 0.f; }

        // reconstruct: S[16l+i] = local_i + a^(i+1) * carry
        f16x8 o0, o1;
        float pd = ad, pm = am;
        #pragma unroll
        for (int i = 0; i < 16; ++i) {
            float yd = fmaf(pd, cd, ld[i]);
            float ym = fmaf(pm, cm, lm[i]);
            float yv = om * (yd - ym);
            if (i < 8) o0[i] = (f16)yv; else o1[i - 8] = (f16)yv;
            pd *= ad; pm *= am;
        }
        f16* dst = y16 + (size_t)row * NT + lane * 16;
        *reinterpret_cast<f16x8*>(dst)     = o0;
        *reinterpret_cast<f16x8*>(dst + 8) = o1;

        __syncthreads();
        if (tid == 0) {
            __threadfence();
            __hip_atomic_store(&cflags[g], MAGIC64,
                               __ATOMIC_RELEASE, __HIP_MEMORY_SCOPE_AGENT);
        }
        return;
    }

    // ================= wprep: W fragment pack (R6 tail body) ==============
    if (g >= NPROD + NCONS) {
        const int wb   = g - (NPROD + NCONS);
        const int gid  = wb * 256 + tid;       // 0..8191
        const int ks8  = gid >> 10;
        const int nt   = (gid >> 6) & 15;
        const int ln   = gid & 63;
        const int nrow = nt * 16 + (ln & 15);
        const int k0   = ks8 * 32 + (ln >> 4) * 8;
        f16x8 v;
        #pragma unroll
        for (int j = 0; j < 8; ++j) {
            int k = k0 + j;
            float wv = W[nrow * 256 + k];
            v[j] = (f16)((k == nrow) ? 0.0f : wv);
        }
        *reinterpret_cast<f16x8*>(wf + (size_t)gid * 8) = v;
        __syncthreads();
        if (tid == 0) {
            __threadfence();
            __hip_atomic_store(&wflags[wb], MAGIC64,
                               __ATOMIC_RELEASE, __HIP_MEMORY_SCOPE_AGENT);
        }
        return;
    }

    // ================= consumers: bilinear (R11 body) ======================
    const int cb = g - NPROD;
    const int tt = cb & 15;
    const int b  = cb >> 4;
    const int t0 = tt * 64;

    // spin-acquire: 64 cohort producer flags + 32 wprep flags
    if (tid < 64) {
        const unsigned long long* f = &cflags[(b << 6) + tid];
        while (__hip_atomic_load(f, __ATOMIC_ACQUIRE,
                                 __HIP_MEMORY_SCOPE_AGENT) != MAGIC64)
            __builtin_amdgcn_s_sleep(8);
    } else if (tid < 96) {
        const unsigned long long* f = &wflags[tid - 64];
        while (__hip_atomic_load(f, __ATOMIC_ACQUIRE,
                                 __HIP_MEMORY_SCOPE_AGENT) != MAGIC64)
            __builtin_amdgcn_s_sleep(8);
    }
    __syncthreads();

    // ---- stage Y tile: thread (j2 = tid&63 -> m = 4*j2+r, h = tid>>6 ->
    //      t in [16h,16h+16)); packed f16x4 writes along m ----
    {
        const int j2 = tid & 63;
        const int h  = tid >> 6;
        const f16* base = y16 + ((size_t)(b * ND + 4 * j2)) * NT + t0 + h * 16;
        f16x8 vy[4][2];
        #pragma unroll
        for (int r = 0; r < 4; ++r) {
            vy[r][0] = *reinterpret_cast<const f16x8*>(base + (size_t)r * NT);
            vy[r][1] = *reinterpret_cast<const f16x8*>(base + (size_t)r * NT + 8);
        }
        #pragma unroll
        for (int i = 0; i < 16; ++i) {
            const int tl = h * 16 + i;
            f16x4 v4;
            v4[0] = vy[0][i >> 3][i & 7];
            v4[1] = vy[1][i >> 3][i & 7];
            v4[2] = vy[2][i >> 3][i & 7];
            v4[3] = vy[3][i >> 3][i & 7];
            *reinterpret_cast<f16x4*>(
                &Yl[tl * 256 + ((4 * j2) ^ ((tl & 7) << 3))]) = v4;
        }
    }
    __syncthreads();

    const int gq = lane >> 4;

    int tl4[4], sw4[4];
    #pragma unroll
    for (int tf = 0; tf < 4; ++tf) {
        tl4[tf] = tf * 16 + (lane & 15);
        sw4[tf] = (tl4[tf] & 7) << 3;
    }

    f32x4 acc[4][4];                    // [a: n-frag][tf]
    #pragma unroll
    for (int a = 0; a < 4; ++a)
        #pragma unroll
        for (int tf = 0; tf < 4; ++tf) acc[a][tf] = (f32x4){0.f,0.f,0.f,0.f};

    // A-frag base for this wave: nt = 4w + a at K-slice ks; stride between
    // consecutive nt (or ks*16) slots is 64 lanes * 8 f16 = 512 f16.
    const f16* wbase = wf + (size_t)(4 * w) * 512 + (size_t)lane * 8;

    f16x8 aA[4], aB[4];
    #pragma unroll
    for (int a_ = 0; a_ < 4; ++a_)
        aA[a_] = *reinterpret_cast<const f16x8*>(wbase + (size_t)a_ * 512);

    #pragma unroll
    for (int kp = 0; kp < 4; ++kp) {
        const int ks0 = 2 * kp, ks1 = 2 * kp + 1;
        // prefetch odd slice
        #pragma unroll
        for (int a_ = 0; a_ < 4; ++a_)
            aB[a_] = *reinterpret_cast<const f16x8*>(
                wbase + (size_t)(ks1 * 16 + a_) * 512);
        // compute even slice
        {
            f16x8 bfrag[4];
            #pragma unroll
            for (int tf = 0; tf < 4; ++tf) {
                int m0 = ks0 * 32 + gq * 8;
                bfrag[tf] = *reinterpret_cast<const f16x8*>(
                    &Yl[tl4[tf] * 256 + (m0 ^ sw4[tf])]);
            }
            #pragma unroll
            for (int a = 0; a < 4; ++a)
                #pragma unroll
                for (int tf = 0; tf < 4; ++tf)
                    acc[a][tf] = __builtin_amdgcn_mfma_f32_16x16x32_f16(
                        aA[a], bfrag[tf], acc[a][tf], 0, 0, 0);
        }
        // prefetch next even slice
        if (kp < 3) {
            #pragma unroll
            for (int a_ = 0; a_ < 4; ++a_)
                aA[a_] = *reinterpret_cast<const f16x8*>(
                    wbase + (size_t)((ks1 + 1) * 16 + a_) * 512);
        }
        // compute odd slice
        {
            f16x8 bfrag[4];
            #pragma unroll
            for (int tf = 0; tf < 4; ++tf) {
                int m0 = ks1 * 32 + gq * 8;
                bfrag[tf] = *reinterpret_cast<const f16x8*>(
                    &Yl[tl4[tf] * 256 + (m0 ^ sw4[tf])]);
            }
            #pragma unroll
            for (int a = 0; a < 4; ++a)
                #pragma unroll
                for (int tf = 0; tf < 4; ++tf)
                    acc[a][tf] = __builtin_amdgcn_mfma_f32_16x16x32_f16(
                        aB[a], bfrag[tf], acc[a][tf], 0, 0, 0);
        }
    }

    // epilogue: per t-col partial = sum over this wave's 64 n of y*(z+1)
    #pragma unroll
    for (int tf = 0; tf < 4; ++tf) {
        float p = 0.f;
        #pragma unroll
        for (int a = 0; a < 4; ++a) {
            int n0 = 64 * w + 16 * a + 4 * gq;
            f16x4 yv4 = *reinterpret_cast<const f16x4*>(
                &Yl[tl4[tf] * 256 + (n0 ^ sw4[tf])]);
            #pragma unroll
            for (int r = 0; r < 4; ++r)
                p = fmaf((float)yv4[r], acc[a][tf][r] + 1.0f, p);
        }
        p += __shfl_xor(p, 16);
        p += __shfl_xor(p, 32);
        if (lane < 16) sbuf[w][tf * 16 + lane] = p;
    }
    __syncthreads();
    if (tid < 64) {
        float s = sbuf[0][tid] + sbuf[1][tid] + sbuf[2][tid] + sbuf[3][tid];
        out[b * NT + t0 + tid] = s - 70.0f;
    }
}

// ---------------------------------------------------------------------------
extern "C" void kernel_launch(void* const* d_in, const int* in_sizes, int n_in,
                              void* d_out, int out_size, void* d_ws, size_t ws_size,
                              hipStream_t stream) {
    const float* x         = (const float*)d_in[0];
    const float* tau_rise  = (const float*)d_in[1];
    const float* tau_decay = (const float*)d_in[2];
    const float* omega     = (const float*)d_in[3];
    const float* W         = (const float*)d_in[4];
    float* out = (float*)d_out;

    f16* y16 = (f16*)d_ws;                                          // 16 MB
    f16* wfr = (f16*)((char*)d_ws + (size_t)16 * 1024 * 1024);      // 128 KB
    unsigned long long* cflags =
        (unsigned long long*)((char*)d_ws + (size_t)17 * 1024 * 1024);  // 16 KB
    unsigned long long* wflags =
        (unsigned long long*)((char*)d_ws + (size_t)17 * 1024 * 1024 + 65536);

    dbnn_mega_kernel<<<NPROD + NCONS + NWPREP, 256, 0, stream>>>(
        x, tau_rise, tau_decay, omega, W, y16, wfr, cflags, wflags, out);
}

// Round 14
// 158.185 us; speedup vs baseline: 1.0186x; 1.0186x over previous
//
#include <hip/hip_runtime.h>

typedef _Float16 f16;
typedef _Float16 f16x4 __attribute__((ext_vector_type(4)));
typedef _Float16 f16x8 __attribute__((ext_vector_type(8)));
typedef float    f32x4 __attribute__((ext_vector_type(4)));

#define NB 32
#define ND 256
#define NT 1024
#define MAGIC64 0x5A5A3C3CA5A5C3C3ull

#define NPROD 2048
#define NCONS 512
#define NWPREP 32

// ---------------------------------------------------------------------------
// ONE dispatch, heterogeneous blocks, slot-counting deadlock freedom (R13)
// + the R12-proven VGPR fix: amdgpu_waves_per_eu(4,4) pins the allocator's
// occupancy target at 4 waves/EU (16 waves/CU = our 4 blocks/CU), so it
// CANNOT squeeze to 64 VGPR and spill (R13: VGPR=64, scratch-bound, 161us).
//
// Slot counting: 256-thr blocks, LDS 33 KB -> 4 blocks/CU -> 1024 resident
// slots; consumers+wprep = 544 < 1024, so >=480 slots always hold runnable
// producers -> progress under ANY dispatch order (G16-safe). Even a
// 3-blocks/CU fallback (VGPR<=170) leaves 768 > 545. Consumer is slimmed to
// ~95 VGPRs (acc[2][4] reused across an nh loop; no A double-buffer;
// staging in two 32-t chunks) to stay far inside that margin.
//
// blocks [0,2048):    producer p: IIR scan rows [4p,4p+4) (R6 body, one
//                     row/wave) -> y16, release cflags[p].
// blocks [2048,2560): consumer cb: b=cb>>4, tt=cb&15. Spin-acquire 64 cohort
//                     cflags + 32 wflags, then bilinear:
//                     out[b,t] = sum_n y[n,t]*(z[n,t]+1) - 70, z = Wm*y.
// blocks [2560,2592): wprep (R6 tail) -> wf, release wflags.
//
// Handoff protocol R6/R9-validated; replay-idempotent (stale MAGIC harmless,
// y16/wf bytes identical every replay).
// ---------------------------------------------------------------------------
__global__
__attribute__((amdgpu_flat_work_group_size(256, 256)))
__attribute__((amdgpu_waves_per_eu(4, 4)))
void dbnn_mega_kernel(
    const float* __restrict__ x, const float* __restrict__ tau_rise,
    const float* __restrict__ tau_decay, const float* __restrict__ omega,
    const float* __restrict__ W, f16* __restrict__ y16, f16* __restrict__ wf,
    unsigned long long* __restrict__ cflags,
    unsigned long long* __restrict__ wflags, float* __restrict__ out)
{
    __shared__ __align__(16) f16 Yl[16384];    // 32 KB (64 t x 256 m)
    __shared__ float sbuf[4][64];              // 1 KB cross-wave partials

    const int g    = blockIdx.x;
    const int tid  = threadIdx.x;
    const int lane = tid & 63;
    const int w    = tid >> 6;

    // ================= producers: IIR scan (R6 node-1 body) ===============
    if (g < NPROD) {
        const int row = g * 4 + w;              // b*ND + n
        const int n   = row & (ND - 1);

        const float td = tau_decay[n];
        const float tr = tau_rise[n];
        const float om = omega[n];
        const float ad = expf(-1.0f / td);
        const float am = expf(-(1.0f / tr + 1.0f / td));

        const float* xr = x + (size_t)row * NT + lane * 16;
        float xv[16];
        #pragma unroll
        for (int i = 0; i < 4; ++i) {
            f32x4 v = *reinterpret_cast<const f32x4*>(xr + i * 4);
            xv[i*4+0] = v[0]; xv[i*4+1] = v[1];
            xv[i*4+2] = v[2]; xv[i*4+3] = v[3];
        }

        float ld[16], lm[16];
        float sd = 0.f, sm = 0.f;
        #pragma unroll
        for (int i = 0; i < 16; ++i) {
            sd = fmaf(ad, sd, xv[i]); ld[i] = sd;
            sm = fmaf(am, sm, xv[i]); lm[i] = sm;
        }

        float t2;
        t2 = ad * ad; t2 = t2 * t2; t2 = t2 * t2; float wd = t2 * t2;
        t2 = am * am; t2 = t2 * t2; t2 = t2 * t2; float wm = t2 * t2;

        float Xd = sd, Xm = sm;
        #pragma unroll
        for (int off = 1; off < 64; off <<= 1) {
            float pd = __shfl_up(Xd, off);
            float pm = __shfl_up(Xm, off);
            if (lane >= off) { Xd = fmaf(wd, pd, Xd); Xm = fmaf(wm, pm, Xm); }
            wd *= wd; wm *= wm;
        }
        float cd = __shfl_up(Xd, 1);
        float cm = __shfl_up(Xm, 1);
        if (lane == 0) { cd = 0.f; cm = 0.f; }

        f16x8 o0, o1;
        float pd = ad, pm = am;
        #pragma unroll
        for (int i = 0; i < 16; ++i) {
            float yd = fmaf(pd, cd, ld[i]);
            float ym = fmaf(pm, cm, lm[i]);
            float yv = om * (yd - ym);
            if (i < 8) o0[i] = (f16)yv; else o1[i - 8] = (f16)yv;
            pd *= ad; pm *= am;
        }
        f16* dst = y16 + (size_t)row * NT + lane * 16;
        *reinterpret_cast<f16x8*>(dst)     = o0;
        *reinterpret_cast<f16x8*>(dst + 8) = o1;

        __syncthreads();
        if (tid == 0) {
            __threadfence();
            __hip_atomic_store(&cflags[g], MAGIC64,
                               __ATOMIC_RELEASE, __HIP_MEMORY_SCOPE_AGENT);
        }
        return;
    }

    // ================= wprep: W fragment pack (R6 tail body) ==============
    if (g >= NPROD + NCONS) {
        const int wb   = g - (NPROD + NCONS);
        const int gid  = wb * 256 + tid;       // 0..8191
        const int ks8  = gid >> 10;
        const int nt   = (gid >> 6) & 15;
        const int ln   = gid & 63;
        const int nrow = nt * 16 + (ln & 15);
        const int k0   = ks8 * 32 + (ln >> 4) * 8;
        f16x8 v;
        #pragma unroll
        for (int j = 0; j < 8; ++j) {
            int k = k0 + j;
            float wv = W[nrow * 256 + k];
            v[j] = (f16)((k == nrow) ? 0.0f : wv);
        }
        *reinterpret_cast<f16x8*>(wf + (size_t)gid * 8) = v;
        __syncthreads();
        if (tid == 0) {
            __threadfence();
            __hip_atomic_store(&wflags[wb], MAGIC64,
                               __ATOMIC_RELEASE, __HIP_MEMORY_SCOPE_AGENT);
        }
        return;
    }

    // ================= consumers: bilinear (lean 4-wave body) ==============
    const int cb = g - NPROD;
    const int tt = cb & 15;
    const int b  = cb >> 4;
    const int t0 = tt * 64;

    // spin-acquire: 64 cohort producer flags + 32 wprep flags
    if (tid < 64) {
        const unsigned long long* f = &cflags[(b << 6) + tid];
        while (__hip_atomic_load(f, __ATOMIC_ACQUIRE,
                                 __HIP_MEMORY_SCOPE_AGENT) != MAGIC64)
            __builtin_amdgcn_s_sleep(8);
    } else if (tid < 96) {
        const unsigned long long* f = &wflags[tid - 64];
        while (__hip_atomic_load(f, __ATOMIC_ACQUIRE,
                                 __HIP_MEMORY_SCOPE_AGENT) != MAGIC64)
            __builtin_amdgcn_s_sleep(8);
    }
    __syncthreads();

    // ---- stage Y tile: thread m = tid, two 32-t chunks (low reg use) ----
    {
        const int m = tid;
        #pragma unroll
        for (int half = 0; half < 2; ++half) {
            const f16* ysrc = y16 + ((size_t)(b * ND + m)) * NT + t0 + half * 32;
            f16x8 vy[4];
            #pragma unroll
            for (int c = 0; c < 4; ++c)
                vy[c] = *reinterpret_cast<const f16x8*>(ysrc + c * 8);
            #pragma unroll
            for (int c = 0; c < 4; ++c) {
                #pragma unroll
                for (int e = 0; e < 8; ++e) {
                    int tl = half * 32 + c * 8 + e;     // tl&7 == e
                    Yl[tl * 256 + (m ^ (e << 3))] = vy[c][e];
                }
            }
        }
    }
    __syncthreads();

    const int gq = lane >> 4;
    int tl4[4], sw4[4];
    #pragma unroll
    for (int tf = 0; tf < 4; ++tf) {
        tl4[tf] = tf * 16 + (lane & 15);
        sw4[tf] = (tl4[tf] & 7) << 3;
    }

    float p4[4] = {0.f, 0.f, 0.f, 0.f};

    #pragma unroll
    for (int nh = 0; nh < 2; ++nh) {
        // this wave's n-range for this half: [nh*128 + 32w, +32)
        f32x4 acc[2][4];                // [a: n-frag][tf]
        #pragma unroll
        for (int a = 0; a < 2; ++a)
            #pragma unroll
            for (int tf = 0; tf < 4; ++tf) acc[a][tf] = (f32x4){0.f,0.f,0.f,0.f};

        #pragma unroll
        for (int ks = 0; ks < 8; ++ks) {
            f16x8 afrag[2];
            #pragma unroll
            for (int a = 0; a < 2; ++a) {
                int nt = nh * 8 + 2 * w + a;
                afrag[a] = *reinterpret_cast<const f16x8*>(
                    &wf[(size_t)((ks * 16 + nt) * 64 + lane) * 8]);
            }
            f16x8 bfrag[4];
            #pragma unroll
            for (int tf = 0; tf < 4; ++tf) {
                int m0 = ks * 32 + gq * 8;
                bfrag[tf] = *reinterpret_cast<const f16x8*>(
                    &Yl[tl4[tf] * 256 + (m0 ^ sw4[tf])]);
            }
            #pragma unroll
            for (int a = 0; a < 2; ++a)
                #pragma unroll
                for (int tf = 0; tf < 4; ++tf)
                    acc[a][tf] = __builtin_amdgcn_mfma_f32_16x16x32_f16(
                        afrag[a], bfrag[tf], acc[a][tf], 0, 0, 0);
        }

        // epilogue: accumulate y*(z+1) over this half's 32 n
        #pragma unroll
        for (int tf = 0; tf < 4; ++tf) {
            #pragma unroll
            for (int a = 0; a < 2; ++a) {
                int n0 = nh * 128 + w * 32 + a * 16 + gq * 4;
                f16x4 yv4 = *reinterpret_cast<const f16x4*>(
                    &Yl[tl4[tf] * 256 + (n0 ^ sw4[tf])]);
                #pragma unroll
                for (int r = 0; r < 4; ++r)
                    p4[tf] = fmaf((float)yv4[r], acc[a][tf][r] + 1.0f, p4[tf]);
            }
        }
    }

    #pragma unroll
    for (int tf = 0; tf < 4; ++tf) {
        float p = p4[tf];
        p += __shfl_xor(p, 16);
        p += __shfl_xor(p, 32);
        if (lane < 16) sbuf[w][tf * 16 + lane] = p;
    }
    __syncthreads();
    if (tid < 64) {
        float s = sbuf[0][tid] + sbuf[1][tid] + sbuf[2][tid] + sbuf[3][tid];
        out[b * NT + t0 + tid] = s - 70.0f;
    }
}

// ---------------------------------------------------------------------------
extern "C" void kernel_launch(void* const* d_in, const int* in_sizes, int n_in,
                              void* d_out, int out_size, void* d_ws, size_t ws_size,
                              hipStream_t stream) {
    const float* x         = (const float*)d_in[0];
    const float* tau_rise  = (const float*)d_in[1];
    const float* tau_decay = (const float*)d_in[2];
    const float* omega     = (const float*)d_in[3];
    const float* W         = (const float*)d_in[4];
    float* out = (float*)d_out;

    f16* y16 = (f16*)d_ws;                                          // 16 MB
    f16* wfr = (f16*)((char*)d_ws + (size_t)16 * 1024 * 1024);      // 128 KB
    unsigned long long* cflags =
        (unsigned long long*)((char*)d_ws + (size_t)17 * 1024 * 1024);  // 16 KB
    unsigned long long* wflags =
        (unsigned long long*)((char*)d_ws + (size_t)17 * 1024 * 1024 + 65536);

    dbnn_mega_kernel<<<NPROD + NCONS + NWPREP, 256, 0, stream>>>(
        x, tau_rise, tau_decay, omega, W, y16, wfr, cflags, wflags, out);
}